// Round 1
// baseline (544.800 us; speedup 1.0000x reference)
//
#include <hip/hip_runtime.h>
#include <cfloat>

#define B_SZ 16
#define CD   256
#define NP   4096
#define KC   1024
#define MT   64
#define NT   64
#define CC   32
#define TPB  256

// numpy pairwise_sum replication for n=256 contiguous-ish access:
// split 128+128, each half: 8 accumulators, combine ((r0+r1)+(r2+r3))+((r4+r5)+(r6+r7)).
// All ops via __f*_rn to forbid FMA contraction / reassociation (must round like np:
// square is rounded to fp32 BEFORE the add, since np materializes w*w first).

__global__ void vq_esq(const float* __restrict__ w, float* __restrict__ esq_g)
{
    int k = blockIdx.x * blockDim.x + threadIdx.x;   // 0..1023
    if (k >= KC) return;
    const float* wr = w + (size_t)k * CD;
    float halves[2];
    #pragma unroll
    for (int h = 0; h < 2; ++h) {
        const float* a = wr + h * 128;
        float r0 = __fmul_rn(a[0], a[0]);
        float r1 = __fmul_rn(a[1], a[1]);
        float r2 = __fmul_rn(a[2], a[2]);
        float r3 = __fmul_rn(a[3], a[3]);
        float r4 = __fmul_rn(a[4], a[4]);
        float r5 = __fmul_rn(a[5], a[5]);
        float r6 = __fmul_rn(a[6], a[6]);
        float r7 = __fmul_rn(a[7], a[7]);
        for (int i = 8; i < 128; i += 8) {
            r0 = __fadd_rn(r0, __fmul_rn(a[i + 0], a[i + 0]));
            r1 = __fadd_rn(r1, __fmul_rn(a[i + 1], a[i + 1]));
            r2 = __fadd_rn(r2, __fmul_rn(a[i + 2], a[i + 2]));
            r3 = __fadd_rn(r3, __fmul_rn(a[i + 3], a[i + 3]));
            r4 = __fadd_rn(r4, __fmul_rn(a[i + 4], a[i + 4]));
            r5 = __fadd_rn(r5, __fmul_rn(a[i + 5], a[i + 5]));
            r6 = __fadd_rn(r6, __fmul_rn(a[i + 6], a[i + 6]));
            r7 = __fadd_rn(r7, __fmul_rn(a[i + 7], a[i + 7]));
        }
        halves[h] = __fadd_rn(__fadd_rn(__fadd_rn(r0, r1), __fadd_rn(r2, r3)),
                              __fadd_rn(__fadd_rn(r4, r5), __fadd_rn(r6, r7)));
    }
    esq_g[k] = __fadd_rn(halves[0], halves[1]);
}

__global__ void __launch_bounds__(TPB, 2)
vq_fused(const float* __restrict__ x, const float* __restrict__ w,
         const float* __restrict__ esq_g, float* __restrict__ out)
{
    __shared__ float xs[CD][MT];        // 64 KB, c-major: xs[c][p]
    __shared__ float ws[CC][NT + 4];    // 8.5 KB, transposed + padded: ws[c][j]
    __shared__ float esq[KC];           // 4 KB
    __shared__ float xsq[MT];
    __shared__ int   codes[MT];

    const int tid = threadIdx.x;
    const int blk = blockIdx.x;        // 0..1023
    const int b   = blk >> 6;
    const int p0  = (blk & 63) << 6;
    const float* xb = x + (size_t)b * CD * NP;

    // ---- stage xs[c][p] (coalesced float4, contiguous LDS writes) ----
    #pragma unroll
    for (int r = 0; r < 16; ++r) {
        int f  = tid + r * TPB;         // float4 slot 0..4095
        int c  = f >> 4;
        int pq = (f & 15) << 2;
        float4 v = *(const float4*)(xb + (size_t)c * NP + p0 + pq);
        *(float4*)&xs[c][pq] = v;
    }
    // ---- load precomputed e_sq ----
    {
        float4 v = *(const float4*)(esq_g + (tid << 2));
        *(float4*)&esq[tid << 2] = v;
    }
    __syncthreads();

    // ---- x_sq per point, np-pairwise order (c = h*128 + i + j) ----
    if (tid < MT) {
        float halves[2];
        #pragma unroll
        for (int h = 0; h < 2; ++h) {
            int cb = h * 128;
            float r0 = __fmul_rn(xs[cb + 0][tid], xs[cb + 0][tid]);
            float r1 = __fmul_rn(xs[cb + 1][tid], xs[cb + 1][tid]);
            float r2 = __fmul_rn(xs[cb + 2][tid], xs[cb + 2][tid]);
            float r3 = __fmul_rn(xs[cb + 3][tid], xs[cb + 3][tid]);
            float r4 = __fmul_rn(xs[cb + 4][tid], xs[cb + 4][tid]);
            float r5 = __fmul_rn(xs[cb + 5][tid], xs[cb + 5][tid]);
            float r6 = __fmul_rn(xs[cb + 6][tid], xs[cb + 6][tid]);
            float r7 = __fmul_rn(xs[cb + 7][tid], xs[cb + 7][tid]);
            for (int i = 8; i < 128; i += 8) {
                r0 = __fadd_rn(r0, __fmul_rn(xs[cb + i + 0][tid], xs[cb + i + 0][tid]));
                r1 = __fadd_rn(r1, __fmul_rn(xs[cb + i + 1][tid], xs[cb + i + 1][tid]));
                r2 = __fadd_rn(r2, __fmul_rn(xs[cb + i + 2][tid], xs[cb + i + 2][tid]));
                r3 = __fadd_rn(r3, __fmul_rn(xs[cb + i + 3][tid], xs[cb + i + 3][tid]));
                r4 = __fadd_rn(r4, __fmul_rn(xs[cb + i + 4][tid], xs[cb + i + 4][tid]));
                r5 = __fadd_rn(r5, __fmul_rn(xs[cb + i + 5][tid], xs[cb + i + 5][tid]));
                r6 = __fadd_rn(r6, __fmul_rn(xs[cb + i + 6][tid], xs[cb + i + 6][tid]));
                r7 = __fadd_rn(r7, __fmul_rn(xs[cb + i + 7][tid], xs[cb + i + 7][tid]));
            }
            halves[h] = __fadd_rn(__fadd_rn(__fadd_rn(r0, r1), __fadd_rn(r2, r3)),
                                  __fadd_rn(__fadd_rn(r4, r5), __fadd_rn(r6, r7)));
        }
        xsq[tid] = __fadd_rn(halves[0], halves[1]);
    }
    // (ordered before first use by the staging barriers inside the n-loop)

    // ---- main fused GEMM + running argmin ----
    float bestd[4] = {FLT_MAX, FLT_MAX, FLT_MAX, FLT_MAX};
    int   besti[4] = {0, 0, 0, 0};
    const int pl = (tid & 15) << 2;     // 4 consecutive local points
    const int jl = (tid >> 4) << 2;     // 4 consecutive local codes

    for (int n0 = 0; n0 < KC; n0 += NT) {
        float acc[4][4];
        #pragma unroll
        for (int i = 0; i < 4; ++i)
            #pragma unroll
            for (int j = 0; j < 4; ++j) acc[i][j] = 0.f;

        for (int c0 = 0; c0 < CD; c0 += CC) {
            __syncthreads();
            {   // stage ws[c][j] = w[n0+j][c0+c]; lanes vary j -> conflict-free LDS writes
                int j  = tid & 63;
                int s0 = (tid >> 6) << 1;
                const float* wr = w + (size_t)(n0 + j) * CD + c0;
                #pragma unroll
                for (int r = 0; r < 2; ++r) {
                    int slot = s0 + r;                       // 0..7 (4 c's each)
                    float4 v = *(const float4*)(wr + (slot << 2));
                    ws[(slot << 2) + 0][j] = v.x;
                    ws[(slot << 2) + 1][j] = v.y;
                    ws[(slot << 2) + 2][j] = v.z;
                    ws[(slot << 2) + 3][j] = v.w;
                }
            }
            __syncthreads();
            #pragma unroll
            for (int c = 0; c < CC; ++c) {
                float4 xv = *(const float4*)&xs[c0 + c][pl];
                float4 wv = *(const float4*)&ws[c][jl];
                acc[0][0] = fmaf(xv.x, wv.x, acc[0][0]);
                acc[0][1] = fmaf(xv.x, wv.y, acc[0][1]);
                acc[0][2] = fmaf(xv.x, wv.z, acc[0][2]);
                acc[0][3] = fmaf(xv.x, wv.w, acc[0][3]);
                acc[1][0] = fmaf(xv.y, wv.x, acc[1][0]);
                acc[1][1] = fmaf(xv.y, wv.y, acc[1][1]);
                acc[1][2] = fmaf(xv.y, wv.z, acc[1][2]);
                acc[1][3] = fmaf(xv.y, wv.w, acc[1][3]);
                acc[2][0] = fmaf(xv.z, wv.x, acc[2][0]);
                acc[2][1] = fmaf(xv.z, wv.y, acc[2][1]);
                acc[2][2] = fmaf(xv.z, wv.z, acc[2][2]);
                acc[2][3] = fmaf(xv.z, wv.w, acc[2][3]);
                acc[3][0] = fmaf(xv.w, wv.x, acc[3][0]);
                acc[3][1] = fmaf(xv.w, wv.y, acc[3][1]);
                acc[3][2] = fmaf(xv.w, wv.z, acc[3][2]);
                acc[3][3] = fmaf(xv.w, wv.w, acc[3][3]);
            }
        }
        // d2 = fl(fl(x_sq - fl(2*cross)) + e_sq)  — exact np op order, no contraction
        #pragma unroll
        for (int i = 0; i < 4; ++i) {
            float xq = xsq[pl + i];
            #pragma unroll
            for (int j = 0; j < 4; ++j) {
                int   idx = n0 + jl + j;
                float d2  = __fadd_rn(__fsub_rn(xq, __fmul_rn(2.0f, acc[i][j])), esq[idx]);
                if (d2 < bestd[i]) { bestd[i] = d2; besti[i] = idx; }   // ascending idx -> first-min kept
            }
        }
    }

    // ---- cross-thread argmin reduction (lexicographic (d2, idx)) ----
    __syncthreads();
    float* redd = &ws[0][0];            // reuse ws: need 2048 floats <= 2176
    int*   redi = (int*)(redd + 1024);
    {
        int g = tid >> 4;               // 0..15 code-groups per point
        #pragma unroll
        for (int i = 0; i < 4; ++i) {
            redd[(pl + i) * 16 + g] = bestd[i];
            redi[(pl + i) * 16 + g] = besti[i];
        }
    }
    __syncthreads();
    if (tid < MT) {
        float bd = FLT_MAX; int bi = 0x7fffffff;
        #pragma unroll
        for (int g = 0; g < 16; ++g) {
            float d = redd[tid * 16 + g];
            int   i = redi[tid * 16 + g];
            if (d < bd || (d == bd && i < bi)) { bd = d; bi = i; }
        }
        codes[tid] = bi;
        out[(size_t)b * NP + p0 + tid] = (float)bi;   // code output as float32
    }
    __syncthreads();

    // ---- gather x_new[b][c][p] = weight[code[p]][c] (coalesced stores) ----
    {
        float* outx = out + (size_t)B_SZ * NP;
        int p  = tid & 63;
        int cg = tid >> 6;
        const float* wr = w + (size_t)codes[p] * CD;
        size_t obase = (size_t)b * CD * NP + (size_t)p0 + p;
        #pragma unroll 4
        for (int r = 0; r < 64; ++r) {
            int c = (cg << 6) + r;
            outx[obase + (size_t)c * NP] = wr[c];
        }
    }
}

extern "C" void kernel_launch(void* const* d_in, const int* in_sizes, int n_in,
                              void* d_out, int out_size, void* d_ws, size_t ws_size,
                              hipStream_t stream)
{
    const float* x = (const float*)d_in[0];     // [16,256,64,64]
    const float* w = (const float*)d_in[1];     // [1024,256]
    float* out    = (float*)d_out;              // 65536 code + 16777216 x_new
    float* esq_g  = (float*)d_ws;               // 4 KB scratch

    hipLaunchKernelGGL(vq_esq,   dim3(4),    dim3(TPB), 0, stream, w, esq_g);
    hipLaunchKernelGGL(vq_fused, dim3(1024), dim3(TPB), 0, stream, x, w, esq_g, out);
}